// Round 5
// baseline (374.281 us; speedup 1.0000x reference)
//
#include <hip/hip_runtime.h>

#define NB 1000000
#define NA 40
#define THREADS 256
#define WPB (THREADS / 64)                      // waves per block
#define NBLOCKS 2048                            // 8 blocks/CU co-resident (round-4 bug: 977 = 3.8/CU)
#define NCHUNKS (NB / 64)                       // 15625, exact (no tail)
#define NEG_LN2_OVER_A (-0.017328679513998632f) // -ln(2)/40

// Round-5: same structure as round 4 (both streams wave-coalesced, in-register
// label transpose, shfl distribution — FETCH_SIZE 156MB, conflicts 0), fixing
// the occupancy bug: round 4 ran 977 blocks = 3.8 blocks/CU, 8 waves/CU avg,
// ~1 outstanding load/wave -> 1.37 TB/s = latency-bound (781k VMEM instrs at
// 92 cyc/instr/CU). Concurrency is the fix: 2048 blocks + launch_bounds(256,6)
// = 24 waves/CU; VGPR cap 85 >= the 84 the compiler already chose (no spill).
__global__ __launch_bounds__(THREADS, 6) void focal_loss_kernel(
    const float* __restrict__ inputs,    // [NB, NA] f32
    const int*   __restrict__ targets,   // [NA, NB] i32 in {0,1}
    const float* __restrict__ attr_w,    // [NA] f32
    float* __restrict__ out)             // [1] f32 (pre-zeroed)
{
    __shared__ float s_red[WPB];
    const int lane = threadIdx.x & 63;
    const int wid  = blockIdx.x * WPB + (threadIdx.x >> 6);
    const int W    = NBLOCKS * WPB;

    // lane-constant slot tables; slots j and j+5 share c(+32), r, weights
    int cj[5], rj[5];
    float4 wt[5];
    #pragma unroll
    for (int j = 0; j < 5; ++j) {
        const int f = lane + 64 * j;
        cj[j] = f / 10;
        rj[j] = 4 * (f - 10 * cj[j]);            // attr base 0,4,...,36
        wt[j] = *(const float4*)(attr_w + rj[j]); // 16B-aligned (rj%4==0)
    }

    float acc = 0.0f;

    for (int ch = wid; ch < NCHUNKS; ch += W) {
        const int s0 = ch * 64;

        // ---- batched coalesced loads: 40 label dwords + 10 input float4 ----
        int lab[NA];
        #pragma unroll
        for (int a = 0; a < NA; ++a)
            lab[a] = targets[(size_t)a * NB + (s0 + lane)];

        const float4* in4 = (const float4*)inputs + (size_t)s0 * 10;
        float4 xv[10];
        #pragma unroll
        for (int j = 0; j < 10; ++j)
            xv[j] = in4[lane + 64 * j];

        // ---- in-register transpose: my sample's 40-bit label word ----
        unsigned wlo = 0u, whi = 0u;
        #pragma unroll
        for (int a = 0; a < 32; ++a) wlo |= (unsigned)(lab[a] & 1) << a;
        #pragma unroll
        for (int a = 32; a < NA; ++a) whi |= (unsigned)(lab[a] & 1) << (a - 32);

        // ---- compute: fetch word of my float4's sample via shfl ----
#define ELEM(X, BIT, AWK) {                                   \
            const float x_  = (X);                            \
            const float om_ = 1.0f - x_;                      \
            const float w_  = (AWK) * (om_ * om_);            \
            const float p_  = fmaxf(x_,  1e-12f);             \
            const float q_  = fmaxf(om_, 1e-12f);             \
            acc = fmaf(w_, __log2f((BIT) ? p_ : q_), acc); }

        #pragma unroll
        for (int j = 0; j < 10; ++j) {
            const int jj = (j < 5) ? j : j - 5;
            const int cs = cj[jj] + ((j < 5) ? 0 : 32);       // source lane
            const unsigned lo = (unsigned)__shfl((int)wlo, cs, 64);
            const unsigned hi = (unsigned)__shfl((int)whi, cs, 64);
            const int r = rj[jj];
            const unsigned nib = ((r < 32) ? (lo >> r) : (hi >> (r - 32))) & 15u;
            const float4 x4 = xv[j];
            const float4 w4 = wt[jj];
            ELEM(x4.x, nib & 1u, w4.x)
            ELEM(x4.y, nib & 2u, w4.y)
            ELEM(x4.z, nib & 4u, w4.z)
            ELEM(x4.w, nib & 8u, w4.w)
        }
#undef ELEM
    }

    // ---- reduce: 64-lane shuffle -> cross-wave LDS -> one atomic/block ----
    float v = acc * NEG_LN2_OVER_A;
    #pragma unroll
    for (int off = 32; off > 0; off >>= 1)
        v += __shfl_xor(v, off, 64);
    const int t = threadIdx.x;
    if ((t & 63) == 0) s_red[t >> 6] = v;
    __syncthreads();
    if (t == 0) {
        float r2 = 0.0f;
        #pragma unroll
        for (int w2 = 0; w2 < WPB; ++w2) r2 += s_red[w2];
        atomicAdd(out, r2);
    }
}

extern "C" void kernel_launch(void* const* d_in, const int* in_sizes, int n_in,
                              void* d_out, int out_size, void* d_ws, size_t ws_size,
                              hipStream_t stream) {
    const float* inputs  = (const float*)d_in[0];
    const int*   targets = (const int*)d_in[1];
    const float* attr_w  = (const float*)d_in[2];
    float* out = (float*)d_out;
    hipMemsetAsync(out, 0, sizeof(float), stream);
    focal_loss_kernel<<<dim3(NBLOCKS), dim3(THREADS), 0, stream>>>(inputs, targets, attr_w, out);
}

// Round 6
// 325.391 us; speedup vs baseline: 1.1502x; 1.1502x over previous
//
#include <hip/hip_runtime.h>

#define NB 1000000
#define NA 40
#define THREADS 256
#define WPB (THREADS / 64)                      // waves per block
#define NBLOCKS 2048                            // 8 blocks/CU queued; VGPR=84 -> 6 blk/CU resident
#define NCHUNKS (NB / 64)                       // 15625, exact (no tail)
#define NEG_LN2_OVER_A (-0.017328679513998632f) // -ln(2)/40

// Round-6 = round-4 structure (both streams wave-coalesced, in-register label
// transpose, shfl distribution: FETCH 156MB, conflicts 0, no spills) + the
// round-5 grid fix (2048 blocks) WITHOUT the launch_bounds(.,6) min-waves
// hint. Round 5 proved the hint forces scratch spills (WRITE_SIZE 0.03->206MB,
// +350MB round-trip traffic); occupancy must come from the grid alone.
// VGPR 84 naturally allows 512/84 = 6 waves/SIMD = 24 waves/CU = 75%.
__global__ __launch_bounds__(THREADS) void focal_loss_kernel(
    const float* __restrict__ inputs,    // [NB, NA] f32
    const int*   __restrict__ targets,   // [NA, NB] i32 in {0,1}
    const float* __restrict__ attr_w,    // [NA] f32
    float* __restrict__ out)             // [1] f32 (pre-zeroed)
{
    __shared__ float s_red[WPB];
    const int lane = threadIdx.x & 63;
    const int wid  = blockIdx.x * WPB + (threadIdx.x >> 6);
    const int W    = NBLOCKS * WPB;

    // lane-constant slot tables; slots j and j+5 share c(+32), r, weights
    int cj[5], rj[5];
    float4 wt[5];
    #pragma unroll
    for (int j = 0; j < 5; ++j) {
        const int f = lane + 64 * j;
        cj[j] = f / 10;
        rj[j] = 4 * (f - 10 * cj[j]);            // attr base 0,4,...,36
        wt[j] = *(const float4*)(attr_w + rj[j]); // 16B-aligned (rj%4==0)
    }

    float acc = 0.0f;

    for (int ch = wid; ch < NCHUNKS; ch += W) {
        const int s0 = ch * 64;

        // ---- batched coalesced loads: 40 label dwords + 10 input float4 ----
        int lab[NA];
        #pragma unroll
        for (int a = 0; a < NA; ++a)
            lab[a] = targets[(size_t)a * NB + (s0 + lane)];

        const float4* in4 = (const float4*)inputs + (size_t)s0 * 10;
        float4 xv[10];
        #pragma unroll
        for (int j = 0; j < 10; ++j)
            xv[j] = in4[lane + 64 * j];

        // ---- in-register transpose: my sample's 40-bit label word ----
        unsigned wlo = 0u, whi = 0u;
        #pragma unroll
        for (int a = 0; a < 32; ++a) wlo |= (unsigned)(lab[a] & 1) << a;
        #pragma unroll
        for (int a = 32; a < NA; ++a) whi |= (unsigned)(lab[a] & 1) << (a - 32);

        // ---- compute: fetch word of my float4's sample via shfl ----
#define ELEM(X, BIT, AWK) {                                   \
            const float x_  = (X);                            \
            const float om_ = 1.0f - x_;                      \
            const float w_  = (AWK) * (om_ * om_);            \
            const float p_  = fmaxf(x_,  1e-12f);             \
            const float q_  = fmaxf(om_, 1e-12f);             \
            acc = fmaf(w_, __log2f((BIT) ? p_ : q_), acc); }

        #pragma unroll
        for (int j = 0; j < 10; ++j) {
            const int jj = (j < 5) ? j : j - 5;
            const int cs = cj[jj] + ((j < 5) ? 0 : 32);       // source lane
            const unsigned lo = (unsigned)__shfl((int)wlo, cs, 64);
            const unsigned hi = (unsigned)__shfl((int)whi, cs, 64);
            const int r = rj[jj];
            const unsigned nib = ((r < 32) ? (lo >> r) : (hi >> (r - 32))) & 15u;
            const float4 x4 = xv[j];
            const float4 w4 = wt[jj];
            ELEM(x4.x, nib & 1u, w4.x)
            ELEM(x4.y, nib & 2u, w4.y)
            ELEM(x4.z, nib & 4u, w4.z)
            ELEM(x4.w, nib & 8u, w4.w)
        }
#undef ELEM
    }

    // ---- reduce: 64-lane shuffle -> cross-wave LDS -> one atomic/block ----
    float v = acc * NEG_LN2_OVER_A;
    #pragma unroll
    for (int off = 32; off > 0; off >>= 1)
        v += __shfl_xor(v, off, 64);
    const int t = threadIdx.x;
    if ((t & 63) == 0) s_red[t >> 6] = v;
    __syncthreads();
    if (t == 0) {
        float r2 = 0.0f;
        #pragma unroll
        for (int w2 = 0; w2 < WPB; ++w2) r2 += s_red[w2];
        atomicAdd(out, r2);
    }
}

extern "C" void kernel_launch(void* const* d_in, const int* in_sizes, int n_in,
                              void* d_out, int out_size, void* d_ws, size_t ws_size,
                              hipStream_t stream) {
    const float* inputs  = (const float*)d_in[0];
    const int*   targets = (const int*)d_in[1];
    const float* attr_w  = (const float*)d_in[2];
    float* out = (float*)d_out;
    hipMemsetAsync(out, 0, sizeof(float), stream);
    focal_loss_kernel<<<dim3(NBLOCKS), dim3(THREADS), 0, stream>>>(inputs, targets, attr_w, out);
}